// Round 2
// baseline (1867.166 us; speedup 1.0000x reference)
//
#include <hip/hip_runtime.h>
#include <math.h>

#define NS 1024
#define NA 2048
#define CIN 16
#define CC 32
#define LL 150
#define LC 75

typedef __attribute__((ext_vector_type(8))) short short8;
typedef __attribute__((ext_vector_type(4))) float float4v;

__device__ __forceinline__ unsigned short f2bf(float f) {
  // round-to-nearest-even fp32 -> bf16
  unsigned int u = __float_as_uint(f);
  unsigned int r = (u + 0x7FFFu + ((u >> 16) & 1u)) >> 16;
  return (unsigned short)r;
}

// ---------------------------------------------------------------------------
// K1: conv1d(k=5,pad=2) + ReLU + sum over 16 reads, as bf16 MFMA implicit GEMM
// (unchanged from round 1 — conflict-free b128 staging, 256 threads)
// ---------------------------------------------------------------------------
__global__ __launch_bounds__(256) void k_conv_sum_mfma(const float* __restrict__ x,
                                                       const float* __restrict__ w,
                                                       float* __restrict__ red) {
  __shared__ unsigned short xs[154 * 32];   // 9856 B = 616 slots of 16B
  const int a = blockIdx.x;
  const int tid = threadIdx.x;
  const int lane = tid & 63;
  const int wv = tid >> 6;

  short8 afr[2][3];
  {
    const int mrow = lane & 15;
    const int h = lane >> 4;
    for (int mt = 0; mt < 2; ++mt) {
      const int c = mt * 16 + mrow;
      for (int s = 0; s < 3; ++s) {
        short8 f;
#pragma unroll
        for (int j = 0; j < 8; ++j) {
          int ic = 4 * h + (j >> 1);
          int tap = 2 * s + (j & 1);
          float wval = (tap < 5) ? w[c * 80 + ic * 5 + tap] : 0.f;
          f[j] = (short)f2bf(wval);
        }
        afr[mt][s] = f;
      }
    }
  }

  float4v sum[2][3];
#pragma unroll
  for (int mt = 0; mt < 2; ++mt)
#pragma unroll
    for (int nt = 0; nt < 3; ++nt) sum[mt][nt] = (float4v)(0.f);

  const int nbase = wv * 48;
  const int nrow = lane & 15;
  const int hh = lane >> 4;
  const float4v zf = (float4v)(0.f);

  for (int r = 0; r < 16; ++r) {
    __syncthreads();
    const float* xr = x + (size_t)(a * 16 + r) * (CIN * LL);
    for (int s = tid; s < 616; s += 256) {
      const int p = s >> 2;
      const int h4 = (s & 3) * 4;
      const float* xb = xr + h4 * LL + p;
      const bool qe_ok = (p >= 2) && (p <= 151);
      const bool qo_ok = (p >= 1) && (p <= 150);
      short8 f;
#pragma unroll
      for (int c = 0; c < 4; ++c) {
        float ve = qe_ok ? xb[c * LL - 2] : 0.f;
        float vo = qo_ok ? xb[c * LL - 1] : 0.f;
        f[2 * c]     = (short)f2bf(ve);
        f[2 * c + 1] = (short)f2bf(vo);
      }
      *(short8*)&xs[s * 8] = f;
    }
    __syncthreads();

    float4v acc[2][3];
#pragma unroll
    for (int s = 0; s < 3; ++s) {
#pragma unroll
      for (int nt = 0; nt < 3; ++nt) {
        int p = nbase + nt * 16 + nrow + 2 * s;
        if (p >= 154) p -= 154;
        short8 bfrag = *(const short8*)&xs[(4 * p + hh) * 8];
#pragma unroll
        for (int mt = 0; mt < 2; ++mt) {
          acc[mt][nt] = __builtin_amdgcn_mfma_f32_16x16x32_bf16(
              afr[mt][s], bfrag, (s == 0) ? zf : acc[mt][nt], 0, 0, 0);
        }
      }
    }
#pragma unroll
    for (int mt = 0; mt < 2; ++mt)
#pragma unroll
      for (int nt = 0; nt < 3; ++nt)
#pragma unroll
        for (int q = 0; q < 4; ++q) sum[mt][nt][q] += fmaxf(acc[mt][nt][q], 0.f);
  }

  const int ccol = lane & 15;
  const int crow4 = (lane >> 4) * 4;
  for (int mt = 0; mt < 2; ++mt)
    for (int nt = 0; nt < 3; ++nt) {
      int l = nbase + nt * 16 + ccol;
      if (l < LL) {
#pragma unroll
        for (int q = 0; q < 4; ++q) {
          int c = mt * 16 + crow4 + q;
          red[(size_t)a * (CC * LL) + c * LL + l] = sum[mt][nt][q];
        }
      }
    }
}

// ---------------------------------------------------------------------------
// K2: red2 = relu(comb_w @ [red0|red1]) in place over red0 (unchanged)
// ---------------------------------------------------------------------------
__global__ __launch_bounds__(256) void k_comb(const float* __restrict__ red0,
                                              const float* __restrict__ red1,
                                              const float* __restrict__ cw,
                                              float* __restrict__ out) {
  __shared__ float ins[64][152];
  __shared__ float cwl[64][CC];
  const int a = blockIdx.x;
  const int tid = threadIdx.x;

  for (int i = tid; i < 64 * CC; i += 256) {
    int c = i & 31; int c2 = i >> 5;
    cwl[c2][c] = cw[c * 64 + c2];
  }
  for (int i = tid; i < CC * LL; i += 256) {
    int c2 = i / LL; int l = i - c2 * LL;
    ins[c2][l] = red0[(size_t)a * (CC * LL) + i];
    ins[32 + c2][l] = red1[(size_t)a * (CC * LL) + i];
  }
  __syncthreads();

  const int c = tid & 31;
  const int lg = tid >> 5;
  const int l0 = lg * 19;
  const int nl = (LL - l0 < 19) ? (LL - l0) : 19;
  float v[19];
#pragma unroll
  for (int j = 0; j < 19; ++j) v[j] = 0.f;
  for (int c2 = 0; c2 < 64; ++c2) {
    float wv = cwl[c2][c];
#pragma unroll
    for (int j = 0; j < 19; ++j) v[j] += wv * ins[c2][l0 + j];
  }
  float* o = out + (size_t)a * (CC * LL) + c * LL + l0;
  for (int j = 0; j < nl; ++j) o[j] = fmaxf(v[j], 0.f);
}

// ---------------------------------------------------------------------------
// K3: compressor conv (k=3, dil=2, stride=2, pad=2) + ReLU (unchanged)
// ---------------------------------------------------------------------------
__global__ __launch_bounds__(256) void k_compress(const float* __restrict__ src,
                                                  const float* __restrict__ w,
                                                  float* __restrict__ dst,
                                                  int site_mode) {
  __shared__ float ins[CC][164];
  __shared__ float ws[CC][3][CC];
  const int n = blockIdx.x;
  const int tid = threadIdx.x;

  for (int i = tid; i < CC * 3 * CC; i += 256) {
    int c = i & 31; int kk = i >> 5; int ic = kk / 3; int t = kk - ic * 3;
    ws[ic][t][c] = w[c * (CC * 3) + ic * 3 + t];
  }
  if (tid < CC) { ins[tid][0] = 0.f; ins[tid][1] = 0.f; ins[tid][152] = 0.f; ins[tid][153] = 0.f; }

  if (site_mode) {
    const float* s0 = src + (size_t)(2 * n) * (CC * LL);
    const float* s1 = src + (size_t)(2 * n + 1) * (CC * LL);
    for (int i = tid; i < CC * LL; i += 256) {
      int ic = i / LL; int l = i - ic * LL;
      ins[ic][l + 2] = s0[i] + s1[i];
    }
  } else {
    const float* s0 = src + (size_t)n * (CC * LL);
    for (int i = tid; i < CC * LL; i += 256) {
      int ic = i / LL; int l = i - ic * LL;
      ins[ic][l + 2] = s0[i];
    }
  }
  __syncthreads();

  const int c = tid & 31;
  const int jg = tid >> 5;
  const int j0 = jg * 10;
  const int nj = (LC - j0 < 10) ? (LC - j0) : 10;
  float v[10];
#pragma unroll
  for (int j = 0; j < 10; ++j) v[j] = 0.f;
  for (int ic = 0; ic < CC; ++ic) {
    float w0 = ws[ic][0][c], w1 = ws[ic][1][c], w2 = ws[ic][2][c];
    float xw[12];
#pragma unroll
    for (int i = 0; i < 12; ++i) xw[i] = ins[ic][2 * j0 + 2 * i];
#pragma unroll
    for (int j = 0; j < 10; ++j) v[j] += w0 * xw[j] + w1 * xw[j + 1] + w2 * xw[j + 2];
  }
  float* o = dst + (size_t)n * (CC * LC) + c * LC + j0;
  for (int j = 0; j < nj; ++j) o[j] = fmaxf(v[j], 0.f);
}

// ---------------------------------------------------------------------------
// K4 v3: per-SITE fused cross-attention (both alleles share k/v).
// 256 threads = 8 groups of 32 lanes. Group g owns row-chunks {g, g+8<=14},
// 5 rows each (15 chunks = rows 0..74 exactly).
// q held in REGISTERS (shfl-broadcast in scores); ctx never materialized —
// each lane accumulates sum_l(cf+ctx) for its channel t directly.
// Arena 74.1 KB -> 2 blocks/CU. Aliases: kb over cf0/cf1 (dead after B1),
// rowp over kv+wq (dead after B2).
// ---------------------------------------------------------------------------
#define AOFF_CF0  0        // [32][77] = 2464
#define AOFF_CF1  2464     // [32][77]          (cf end 4928)
#define AOFF_KV   4928     // [32][152] = 4864  (end 9792)
#define AOFF_W    9792     // 3 x [32][33] in-major (wq,wk,wv), end 12960
#define AOFF_VB   12960    // [32][156] = 4992  (end 17952), float4-aligned
#define AOFF_PART 17952    // [2][8][32] = 512  (end 18464)
#define AOFF_MS   18464    // [2][32] = 64      (end 18528)
#define AOFF_KB   0        // alias over cf0+cf1: [32][154] = 4928 (exact)
#define AOFF_ROWP 4928     // alias over kv+wq: [8*5][152] = 6080 (ends 11008)
#define ARENA2_F  18528    // 74112 B

__device__ __forceinline__ void qcomp(const float* ar, int cfb, int jrow, int t,
                                      const float (&wqc)[32], float (&qo)[5],
                                      float& csum) {
#pragma unroll
  for (int i = 0; i < 5; ++i) {
    const int row = jrow * 5 + i;
    float a = 0.f;
#pragma unroll
    for (int ii = 0; ii < 32; ++ii) a += wqc[ii] * ar[cfb + ii * 77 + row];
    qo[i] = a;
    csum += ar[cfb + t * 77 + row];
  }
}

__device__ __forceinline__ void attn_chunk(float* ar, const float (&q)[5],
                                           int t, int g, const int (&mcl)[5],
                                           float& msum) {
  const float scale = 0.17677669529663687f;   // 1/sqrt(32)
  // ---- scores: acc[i][u] = sum_c q[c][row_i] * k[c][m=t+32u] ----
  float acc[5][5];
#pragma unroll
  for (int i = 0; i < 5; ++i)
#pragma unroll
    for (int u = 0; u < 5; ++u) acc[i][u] = 0.f;
#pragma unroll 4
  for (int c2 = 0; c2 < 32; ++c2) {
    float kk[5];
#pragma unroll
    for (int u = 0; u < 5; ++u) kk[u] = ar[AOFF_KB + c2 * 154 + mcl[u]];
#pragma unroll
    for (int i = 0; i < 5; ++i) {
      float qv = __shfl(q[i], c2, 32);
#pragma unroll
      for (int u = 0; u < 5; ++u) acc[i][u] += qv * kk[u];
    }
  }
  // ---- softmax per row (unnormalized p -> rowp; inv kept) ----
  float inv[5];
  const int rbase = AOFF_ROWP + g * 5 * 152;
#pragma unroll
  for (int i = 0; i < 5; ++i) {
    float sc[5];
#pragma unroll
    for (int u = 0; u < 5; ++u) sc[u] = acc[i][u] * scale;
    if (t >= 22) sc[4] = -1e30f;                 // m = t+128 >= 150
    float mx = fmaxf(fmaxf(fmaxf(sc[0], sc[1]), fmaxf(sc[2], sc[3])), sc[4]);
#pragma unroll
    for (int off = 16; off > 0; off >>= 1) mx = fmaxf(mx, __shfl_xor(mx, off, 32));
    float p[5], ss = 0.f;
#pragma unroll
    for (int u = 0; u < 5; ++u) { p[u] = __expf(sc[u] - mx); ss += p[u]; }
#pragma unroll
    for (int off = 16; off > 0; off >>= 1) ss += __shfl_xor(ss, off, 32);
    inv[i] = 1.f / ss;
    const int rb = rbase + i * 152;
#pragma unroll
    for (int u = 0; u < 4; ++u) ar[rb + t + 32 * u] = p[u];
    if (t < 22) ar[rb + t + 128] = p[4];
  }
  // ---- PV: acc2[i] = sum_m p[row_i][m] * v[t][m]  (float4) ----
  float acc2[5];
#pragma unroll
  for (int i = 0; i < 5; ++i) acc2[i] = 0.f;
  const int vbase = AOFF_VB + t * 156;
#pragma unroll 2
  for (int mq = 0; mq < 37; ++mq) {
    float4 vv = *(const float4*)&ar[vbase + 4 * mq];
#pragma unroll
    for (int i = 0; i < 5; ++i) {
      float4 pp = *(const float4*)&ar[rbase + i * 152 + 4 * mq];
      acc2[i] += pp.x * vv.x + pp.y * vv.y + pp.z * vv.z + pp.w * vv.w;
    }
  }
  {
    float2 vt = *(const float2*)&ar[vbase + 148];
#pragma unroll
    for (int i = 0; i < 5; ++i) {
      float2 pt = *(const float2*)&ar[rbase + i * 152 + 148];
      acc2[i] += pt.x * vt.x + pt.y * vt.y;
    }
  }
#pragma unroll
  for (int i = 0; i < 5; ++i) msum += acc2[i] * inv[i];
}

__global__ __launch_bounds__(256) void k_attn(const float* __restrict__ cfa,
                                              const float* __restrict__ cfs0,
                                              const float* __restrict__ wq,
                                              const float* __restrict__ wk,
                                              const float* __restrict__ wv,
                                              const float* __restrict__ wo,
                                              float* __restrict__ eout) {
  __shared__ float ar[ARENA2_F];
  const int s = blockIdx.x;
  const int tid = threadIdx.x;
  const int g = tid >> 5;
  const int t = tid & 31;

  // ---- phase A: stage cf0, cf1, kv(=[cfs0 | cf0+cf1]), weights ----
  const float* cf0g = cfa + (size_t)(2 * s) * (CC * LC);
  const float* cf1g = cf0g + CC * LC;
  const float* kvg  = cfs0 + (size_t)s * (CC * LC);
  for (int i = tid; i < CC * LC; i += 256) {
    int c = i / 75, l = i - c * 75;
    float v0 = cf0g[i], v1 = cf1g[i];
    ar[AOFF_CF0 + c * 77 + l] = v0;
    ar[AOFF_CF1 + c * 77 + l] = v1;
    ar[AOFF_KV + c * 152 + l] = kvg[i];
    ar[AOFF_KV + c * 152 + 75 + l] = v0 + v1;
  }
  for (int i = tid; i < CC * CC; i += 256) {
    int o = i >> 5, c = i & 31;
    ar[AOFF_W + c * 33 + o]        = wq[i];   // in-major, padded stride 33
    ar[AOFF_W + 1056 + c * 33 + o] = wk[i];
    ar[AOFF_W + 2112 + c * 33 + o] = wv[i];
  }
  __syncthreads();

  // ---- phase B1: q -> registers (per-group rows), cf column-sums ----
  float q0A[5] = {0, 0, 0, 0, 0}, q0B[5] = {0, 0, 0, 0, 0};
  float q1A[5] = {0, 0, 0, 0, 0}, q1B[5] = {0, 0, 0, 0, 0};
  float cfsum0 = 0.f, cfsum1 = 0.f;
  {
    float wqc[32];
#pragma unroll
    for (int ii = 0; ii < 32; ++ii) wqc[ii] = ar[AOFF_W + ii * 33 + t];
    qcomp(ar, AOFF_CF0, g, t, wqc, q0A, cfsum0);
    if (g < 7) qcomp(ar, AOFF_CF0, g + 8, t, wqc, q0B, cfsum0);
    qcomp(ar, AOFF_CF1, g, t, wqc, q1A, cfsum1);
    if (g < 7) qcomp(ar, AOFF_CF1, g + 8, t, wqc, q1B, cfsum1);
  }
  __syncthreads();   // cf reads done -> kb may overwrite cf region

  // ---- phase B2: k, v projections (shared by both alleles) ----
  {
    float wkc[32], wvc[32];
#pragma unroll
    for (int ii = 0; ii < 32; ++ii) {
      wkc[ii] = ar[AOFF_W + 1056 + ii * 33 + t];
      wvc[ii] = ar[AOFF_W + 2112 + ii * 33 + t];
    }
    for (int idx = tid; idx < CC * LL; idx += 256) {
      int o = idx & 31, m = idx >> 5;
      float ka = 0.f, va = 0.f;
#pragma unroll
      for (int ii = 0; ii < 32; ++ii) {
        float kvv = ar[AOFF_KV + ii * 152 + m];
        ka += wkc[ii] * kvv;
        va += wvc[ii] * kvv;
      }
      ar[AOFF_KB + o * 154 + m] = ka;
      ar[AOFF_VB + o * 156 + m] = va;
    }
  }
  __syncthreads();   // kb/vb ready; kv+wq now dead -> rowp may overwrite

  // ---- phase D: scores -> softmax -> PV, fused mean accumulation ----
  int mcl[5];
#pragma unroll
  for (int u = 0; u < 5; ++u) { int m = t + 32 * u; mcl[u] = (m < 150) ? m : 149; }

  float ms0 = 0.f, ms1 = 0.f;
  attn_chunk(ar, q0A, t, g, mcl, ms0);
  if (g < 7) attn_chunk(ar, q0B, t, g, mcl, ms0);
  attn_chunk(ar, q1A, t, g, mcl, ms1);
  if (g < 7) attn_chunk(ar, q1B, t, g, mcl, ms1);

  ar[AOFF_PART + g * 32 + t]       = cfsum0 + ms0;
  ar[AOFF_PART + 256 + g * 32 + t] = cfsum1 + ms1;
  __syncthreads();

  // ---- epilogue: mean over l, project with wo ----
  if (tid < 64) {
    int al = tid >> 5, tt = tid & 31;
    float tot = 0.f;
#pragma unroll
    for (int gg = 0; gg < 8; ++gg) tot += ar[AOFF_PART + al * 256 + gg * 32 + tt];
    ar[AOFF_MS + al * 32 + tt] = tot * (1.f / 75.f);
  }
  __syncthreads();
  if (tid < 4) {
    int al = tid >> 1, o2 = tid & 1;
    float e = 0.f;
#pragma unroll
    for (int c2 = 0; c2 < 32; ++c2) e += wo[o2 * 32 + c2] * ar[AOFF_MS + al * 32 + c2];
    eout[s * 4 + tid] = e;   // = eout[(2s+al)*2 + o2]
  }
}

// ---------------------------------------------------------------------------
// K5: meta head per site (unchanged)
// ---------------------------------------------------------------------------
__global__ __launch_bounds__(64) void k_meta(const float* __restrict__ cfs0,
                                             const float* __restrict__ cfa2,
                                             const float* __restrict__ mw,
                                             const float* __restrict__ mb,
                                             float* __restrict__ mout) {
  __shared__ float feat[64];
  __shared__ float lgt[3];
  const int s = blockIdx.x;
  const int tid = threadIdx.x;
  float f = 0.f;
  if (tid < 32) {
    const float* p = cfs0 + (size_t)s * (CC * LC) + tid * LC;
    for (int l = 0; l < LC; ++l) f += p[l];
  } else {
    const float* p0 = cfa2 + (size_t)(2 * s) * (CC * LC) + (tid - 32) * LC;
    const float* p1 = cfa2 + (size_t)(2 * s + 1) * (CC * LC) + (tid - 32) * LC;
    for (int l = 0; l < LC; ++l) f += p0[l] + p1[l];
  }
  feat[tid] = f * (1.f / 75.f);
  __syncthreads();
  if (tid < 3) {
    float acc2 = mb[tid];
    for (int c2 = 0; c2 < 64; ++c2) acc2 += mw[tid * 64 + c2] * feat[c2];
    lgt[tid] = acc2;
  }
  __syncthreads();
  if (tid < 3) {
    float mx = fmaxf(lgt[0], fmaxf(lgt[1], lgt[2]));
    float e0 = __expf(lgt[0] - mx), e1 = __expf(lgt[1] - mx), e2 = __expf(lgt[2] - mx);
    mout[s * 3 + tid] = __expf(lgt[tid] - mx) / (e0 + e1 + e2);
  }
}

// ---------------------------------------------------------------------------
extern "C" void kernel_launch(void* const* d_in, const int* in_sizes, int n_in,
                              void* d_out, int out_size, void* d_ws, size_t ws_size,
                              hipStream_t stream) {
  const float* t0      = (const float*)d_in[0];
  const float* t1      = (const float*)d_in[1];
  const float* conv0_w = (const float*)d_in[2];
  const float* conv1_w = (const float*)d_in[3];
  const float* comp0_w = (const float*)d_in[4];
  const float* comp1_w = (const float*)d_in[5];
  const float* comp2_w = (const float*)d_in[6];
  const float* xq0 = (const float*)d_in[7];
  const float* xk0 = (const float*)d_in[8];
  const float* xv0 = (const float*)d_in[9];
  const float* xo0 = (const float*)d_in[10];
  const float* xq1 = (const float*)d_in[11];
  const float* xk1 = (const float*)d_in[12];
  const float* xv1 = (const float*)d_in[13];
  const float* xo1 = (const float*)d_in[14];
  const float* xq2 = (const float*)d_in[15];
  const float* xk2 = (const float*)d_in[16];
  const float* xv2 = (const float*)d_in[17];
  const float* xo2 = (const float*)d_in[18];
  const float* comb_w = (const float*)d_in[19];
  const float* meta_w = (const float*)d_in[20];
  const float* meta_b = (const float*)d_in[21];

  float* wsf  = (float*)d_ws;
  float* red0 = wsf;
  float* red1 = red0 + (size_t)NA * CC * LL;
  float* cfa  = red1 + (size_t)NA * CC * LL;
  float* cfs0 = cfa + (size_t)NA * CC * LC;
  float* out  = (float*)d_out;

  k_conv_sum_mfma<<<NA, 256, 0, stream>>>(t0, conv0_w, red0);
  k_conv_sum_mfma<<<NA, 256, 0, stream>>>(t1, conv1_w, red1);

  k_compress<<<NA, 256, 0, stream>>>(red0, comp0_w, cfa, 0);
  k_compress<<<NS, 256, 0, stream>>>(red0, comp0_w, cfs0, 1);
  k_attn<<<NS, 256, 0, stream>>>(cfa, cfs0, xq0, xk0, xv0, xo0, out + 0);

  k_compress<<<NA, 256, 0, stream>>>(red1, comp1_w, cfa, 0);
  k_compress<<<NS, 256, 0, stream>>>(red1, comp1_w, cfs0, 1);
  k_attn<<<NS, 256, 0, stream>>>(cfa, cfs0, xq1, xk1, xv1, xo1, out + 2 * NA);

  k_comb<<<NA, 256, 0, stream>>>(red0, red1, comb_w, red0);
  k_compress<<<NA, 256, 0, stream>>>(red0, comp2_w, cfa, 0);
  k_compress<<<NS, 256, 0, stream>>>(red0, comp2_w, cfs0, 1);
  k_attn<<<NS, 256, 0, stream>>>(cfa, cfs0, xq2, xk2, xv2, xo2, out + 4 * NA);

  k_meta<<<NS, 64, 0, stream>>>(cfs0, cfa, meta_w, meta_b, out + 6 * NA);
}